// Round 3
// baseline (1643.143 us; speedup 1.0000x reference)
//
#include <hip/hip_runtime.h>
#include <hip/hip_bf16.h>

#define HID     256
#define NNODES  50000
#define NEDGES  300000
#define NGRAPHS 128
#define L       4

typedef __attribute__((ext_vector_type(8))) short bf16x8;
typedef __attribute__((ext_vector_type(4))) float f32x4;
typedef __attribute__((ext_vector_type(4))) unsigned short u16x4;

static __device__ __forceinline__ float b2f(unsigned short s) {
    union { unsigned u; float f; } v;
    v.u = ((unsigned)s) << 16;
    return v.f;
}
static __device__ __forceinline__ short f2b(float f) {
    __hip_bfloat16 h = __float2bfloat16(f);
    return *reinterpret_cast<short*>(&h);
}

// ------------------------------------------------ weight convert + transpose
__global__ void wconv_k(const float* __restrict__ w, short* __restrict__ wT) {
    int m = blockIdx.y, n = blockIdx.x, k = threadIdx.x;
    wT[(size_t)m * 65536 + n * 256 + k] = f2b(w[(size_t)m * 65536 + k * 256 + n]);
}

// ---------------------------------------------------------------- node embed
__global__ void node_embed_k(const float* __restrict__ x,
                             const float* __restrict__ w,
                             const float* __restrict__ b,
                             short* __restrict__ hb) {
    int n = blockIdx.x;
    int j = threadIdx.x;
    __shared__ float xr[32];
    if (j < 32) xr[j] = x[n * 32 + j];
    __syncthreads();
    float acc = b[j];
#pragma unroll
    for (int k = 0; k < 32; ++k) acc = fmaf(xr[k], w[k * HID + j], acc);
    hb[(size_t)n * HID + j] = f2b(acc);
}

// ------------------------------------------------------------- CSR building
__global__ void deg_k(const int* __restrict__ ei, int* __restrict__ deg) {
    int e = blockIdx.x * 256 + threadIdx.x;
    if (e < NEDGES) atomicAdd(&deg[ei[NEDGES + e]], 1);
}

__global__ void scan1_k(const int* __restrict__ deg, int* __restrict__ partial,
                        int* __restrict__ btot) {
    __shared__ int s[256];
    int t = threadIdx.x;
    int gi = blockIdx.x * 256 + t;
    s[t] = (gi < NNODES) ? deg[gi] : 0;
    __syncthreads();
    for (int off = 1; off < 256; off <<= 1) {
        int u = (t >= off) ? s[t - off] : 0;
        __syncthreads();
        s[t] += u;
        __syncthreads();
    }
    if (gi < NNODES) partial[gi] = s[t];
    if (t == 255) btot[blockIdx.x] = s[255];
}

__global__ void scan2_k(int* __restrict__ btot, int nb) {
    __shared__ int s[256];
    int t = threadIdx.x;
    s[t] = (t < nb) ? btot[t] : 0;
    __syncthreads();
    for (int off = 1; off < 256; off <<= 1) {
        int u = (t >= off) ? s[t - off] : 0;
        __syncthreads();
        s[t] += u;
        __syncthreads();
    }
    btot[t] = s[t];
}

__global__ void scan3_k(const int* __restrict__ deg, const int* __restrict__ partial,
                        const int* __restrict__ btot, int* __restrict__ row_ptr,
                        int* __restrict__ cursor) {
    int gi = blockIdx.x * 256 + threadIdx.x;
    if (gi >= NNODES) return;
    int b = blockIdx.x;
    int incl = partial[gi] + (b ? btot[b - 1] : 0);
    int start = incl - deg[gi];
    row_ptr[gi] = start;
    cursor[gi] = start;
    if (gi == NNODES - 1) row_ptr[NNODES] = incl;
}

__global__ void fill_k(const int* __restrict__ ei, int* __restrict__ cursor,
                       int* __restrict__ eid) {
    int e = blockIdx.x * 256 + threadIdx.x;
    if (e < NEDGES) {
        int d = ei[NEDGES + e];
        int pos = atomicAdd(&cursor[d], 1);
        eid[pos] = e;
    }
}

// --------------------------------------- permute eattr/src into CSR slot order
__global__ void esort_k(const float* __restrict__ eattr, const int* __restrict__ ei,
                        const int* __restrict__ eid, float* __restrict__ eattr_s,
                        int* __restrict__ srcs) {
    int t = blockIdx.x * 16 + (threadIdx.x >> 4);
    int k = threadIdx.x & 15;
    if (t < NEDGES) {
        int e = eid[t];
        eattr_s[(size_t)t * 16 + k] = eattr[(size_t)e * 16 + k];
        if (k == 0) srcs[t] = ei[e];
    }
}

// ------------------------------------------------- CSR aggregate, wave-per-node
// zb[n] = hb[n] + sum_edges relu(hb[src] + eattr_s[t]@ew + eb)
#define AGG_NPW 4
__global__ __launch_bounds__(256) void agg_k(
    const short* __restrict__ hb, const float* __restrict__ eattr_s,
    const int* __restrict__ srcs, const int* __restrict__ row_ptr,
    const float* __restrict__ ew, const float* __restrict__ ebias,
    short* __restrict__ zb) {
    int lane = threadIdx.x & 63, wv = threadIdx.x >> 6;
    int c = lane * 4;
    // edge_w columns for this lane, in registers (static indexing only)
    float ewv[16][4];
#pragma unroll
    for (int k = 0; k < 16; ++k) {
        float4 v = *reinterpret_cast<const float4*>(ew + k * 256 + c);
        ewv[k][0] = v.x; ewv[k][1] = v.y; ewv[k][2] = v.z; ewv[k][3] = v.w;
    }
    float4 ebv = *reinterpret_cast<const float4*>(ebias + c);
    float eb0 = ebv.x, eb1 = ebv.y, eb2 = ebv.z, eb3 = ebv.w;

    int n0 = (blockIdx.x * 4 + wv) * AGG_NPW;
    int n1 = min(n0 + AGG_NPW, NNODES);
    for (int n = n0; n < n1; ++n) {
        u16x4 h4 = *reinterpret_cast<const u16x4*>(hb + (size_t)n * HID + c);
        float acc[4];
#pragma unroll
        for (int i = 0; i < 4; ++i) acc[i] = b2f(h4[i]);
        int beg = row_ptr[n], end = row_ptr[n + 1];
        for (int t = beg; t < end; ++t) {
            int s = srcs[t];
            const float4* ep = reinterpret_cast<const float4*>(eattr_s + (size_t)t * 16);
            float4 q0 = ep[0], q1 = ep[1], q2 = ep[2], q3 = ep[3];
            u16x4 hs = *reinterpret_cast<const u16x4*>(hb + (size_t)s * HID + c);
            float m[4] = { eb0 + b2f(hs[0]), eb1 + b2f(hs[1]),
                           eb2 + b2f(hs[2]), eb3 + b2f(hs[3]) };
            float ek[16] = { q0.x, q0.y, q0.z, q0.w, q1.x, q1.y, q1.z, q1.w,
                             q2.x, q2.y, q2.z, q2.w, q3.x, q3.y, q3.z, q3.w };
#pragma unroll
            for (int k = 0; k < 16; ++k)
#pragma unroll
                for (int i = 0; i < 4; ++i) m[i] = fmaf(ek[k], ewv[k][i], m[i]);
#pragma unroll
            for (int i = 0; i < 4; ++i) acc[i] += fmaxf(m[i], 0.f);
        }
        u16x4 o;
#pragma unroll
        for (int i = 0; i < 4; ++i) o[i] = (unsigned short)f2b(acc[i]);
        *reinterpret_cast<u16x4*>(zb + (size_t)n * HID + c) = o;
    }
}

// ----------------------------------------------------------- bf16 MFMA GEMM
// C[M,256] = act(A@W + bias); BM=128 (4 waves x 32 rows), BN=256 (A read once).
// STATS: fuse BN batch-stats (sum, sumsq per column) via shfl + atomics.
template <bool RELU, bool STATS>
__global__ __launch_bounds__(256) void gemm_k(const short* __restrict__ A,
                                              const short* __restrict__ wT,
                                              const float* __restrict__ bias,
                                              short* __restrict__ C,
                                              float* __restrict__ stats, int M) {
    int wv = threadIdx.x >> 6, lane = threadIdx.x & 63;
    int lr = lane & 15, lg = lane >> 4;
    int r0 = blockIdx.x * 128 + wv * 32;
    int rA0 = r0 + lr, rA1 = r0 + 16 + lr;
    bool g0 = rA0 < M, g1 = rA1 < M;
    const short* pA0 = A + (size_t)rA0 * 256 + lg * 8;
    const short* pA1 = A + (size_t)rA1 * 256 + lg * 8;
    const short* pB  = wT + (size_t)lr * 256 + lg * 8;

    f32x4 acc[2][16] = {};

    for (int k0 = 0; k0 < 256; k0 += 32) {
        bf16x8 a0 = {}, a1 = {};
        if (g0) a0 = *reinterpret_cast<const bf16x8*>(pA0 + k0);
        if (g1) a1 = *reinterpret_cast<const bf16x8*>(pA1 + k0);
#pragma unroll
        for (int cc = 0; cc < 16; ++cc) {
            bf16x8 b = *reinterpret_cast<const bf16x8*>(pB + (size_t)cc * 16 * 256 + k0);
            acc[0][cc] = __builtin_amdgcn_mfma_f32_16x16x32_bf16(a0, b, acc[0][cc], 0, 0, 0);
            acc[1][cc] = __builtin_amdgcn_mfma_f32_16x16x32_bf16(a1, b, acc[1][cc], 0, 0, 0);
        }
    }

#pragma unroll
    for (int cc = 0; cc < 16; ++cc) {
        int col = cc * 16 + lr;
        float bi = bias[col];
        float s = 0.f, ss = 0.f;
#pragma unroll
        for (int r = 0; r < 2; ++r)
#pragma unroll
            for (int i = 0; i < 4; ++i) {
                int row = r0 + r * 16 + lg * 4 + i;
                if (row < M) {
                    float v = acc[r][cc][i] + bi;
                    if (RELU) v = fmaxf(v, 0.f);
                    C[(size_t)row * 256 + col] = f2b(v);
                    if (STATS) { s += v; ss = fmaf(v, v, ss); }
                }
            }
        if (STATS) {
            s  += __shfl_xor(s, 16);  ss += __shfl_xor(ss, 16);
            s  += __shfl_xor(s, 32);  ss += __shfl_xor(ss, 32);
            if (lg == 0) {
                atomicAdd(&stats[col], s);
                atomicAdd(&stats[HID + col], ss);
            }
        }
    }
}

// ------------------------------------------------------- BN normalize+relu
__global__ void bn_relu_k(const short* __restrict__ z, short* __restrict__ hb,
                          const float* __restrict__ stats,
                          const float* __restrict__ gamma,
                          const float* __restrict__ beta) {
    int gidx = blockIdx.x * 256 + threadIdx.x; // one per 4 elements
    int base = gidx * 4;
    int j = base & 255;
    u16x4 z4 = *reinterpret_cast<const u16x4*>(z + base);
    u16x4 o;
#pragma unroll
    for (int i = 0; i < 4; ++i) {
        float mu  = stats[j + i] * (1.f / NNODES);
        float var = stats[HID + j + i] * (1.f / NNODES) - mu * mu;
        float inv = rsqrtf(var + 1e-5f);
        float v = (b2f(z4[i]) - mu) * inv * gamma[j + i] + beta[j + i];
        o[i] = (unsigned short)f2b(fmaxf(v, 0.f));
    }
    *reinterpret_cast<u16x4*>(hb + base) = o;
}

// ------------------------------------------------------------------ pool
// batch is sorted -> run-length accumulate, few atomics.
#define PNB 64
__global__ void pool_k(const short* __restrict__ hb, const int* __restrict__ batch,
                       float* __restrict__ g) {
    int j = threadIdx.x;
    int n0 = blockIdx.x * PNB;
    int n1 = min(n0 + PNB, NNODES);
    int cur = batch[n0];
    float acc = 0.f;
    for (int n = n0; n < n1; ++n) {
        int b = batch[n];
        if (b != cur) {
            atomicAdd(&g[(size_t)cur * HID + j], acc);
            acc = 0.f; cur = b;
        }
        acc += b2f((unsigned short)hb[(size_t)n * HID + j]);
    }
    atomicAdd(&g[(size_t)cur * HID + j], acc);
}

// ------------------------------------------------------------------ head
__global__ void head_k(const float* __restrict__ g, const float* __restrict__ w1,
                       const float* __restrict__ b1, const float* __restrict__ w2,
                       const float* __restrict__ b2, float* __restrict__ out) {
    int gi = blockIdx.x;
    int j  = threadIdx.x;
    __shared__ float gr[256];
    __shared__ float hid[128];
    gr[j]       = g[gi * 256 + j];
    gr[j + 128] = g[gi * 256 + 128 + j];
    __syncthreads();
    float acc = b1[j];
    for (int k = 0; k < 256; ++k) acc = fmaf(gr[k], w1[k * 128 + j], acc);
    hid[j] = fmaxf(acc, 0.f);
    __syncthreads();
    if (j < 12) {
        float o = b2[j];
#pragma unroll
        for (int k = 0; k < 128; ++k) o = fmaf(hid[k], w2[k * 12 + j], o);
        out[gi * 12 + j] = o;
    }
}

// ---------------------------------------------------------------- launch
extern "C" void kernel_launch(void* const* d_in, const int* in_sizes, int n_in,
                              void* d_out, int out_size, void* d_ws, size_t ws_size,
                              hipStream_t stream) {
    const float* x     = (const float*)d_in[0];
    const int*   ei    = (const int*)d_in[1];
    const int*   batch = (const int*)d_in[2];
    const float* eattr = (const float*)d_in[3];
    const float* nw    = (const float*)d_in[4];
    const float* nb    = (const float*)d_in[5];
    const float* ew    = (const float*)d_in[6];
    const float* eb    = (const float*)d_in[7];
    const float* w1    = (const float*)d_in[8];
    const float* b1    = (const float*)d_in[9];
    const float* w2    = (const float*)d_in[10];
    const float* b2    = (const float*)d_in[11];
    const float* gam   = (const float*)d_in[12];
    const float* bet   = (const float*)d_in[13];
    const float* hw1   = (const float*)d_in[14];
    const float* hb1   = (const float*)d_in[15];
    const float* hw2   = (const float*)d_in[16];
    const float* hb2   = (const float*)d_in[17];
    float* out = (float*)d_out;

    const size_t NH = (size_t)NNODES * HID;
    size_t off = 0;
    char* base = (char*)d_ws;
    auto alloc = [&](size_t bytes) -> void* {
        void* p = base + off;
        off += (bytes + 255) & ~(size_t)255;
        return p;
    };
    short* hb      = (short*)alloc(NH * 2);
    short* zb      = (short*)alloc(NH * 2);   // aggregate out; later gemm2 out
    short* z1b     = (short*)alloc(NH * 2);
    short* wT      = (short*)alloc(8 * 65536 * 2);
    float* eattr_s = (float*)alloc((size_t)NEDGES * 16 * 4);
    int*   srcs    = (int*)alloc((size_t)NEDGES * 4);
    float* stats   = (float*)alloc(512 * 4);
    float* g       = (float*)alloc((size_t)NGRAPHS * HID * 4);
    int*   deg     = (int*)alloc((size_t)NNODES * 4);
    int*   partial = (int*)alloc((size_t)NNODES * 4);
    int*   btot    = (int*)alloc(256 * 4);
    int*   row_ptr = (int*)alloc((size_t)(NNODES + 1) * 4);
    int*   cursor  = (int*)alloc((size_t)NNODES * 4);
    int*   eid     = (int*)alloc((size_t)NEDGES * 4);

    wconv_k<<<dim3(256, 4), 256, 0, stream>>>(w1, wT);
    wconv_k<<<dim3(256, 4), 256, 0, stream>>>(w2, wT + 4 * 65536);
    node_embed_k<<<NNODES, 256, 0, stream>>>(x, nw, nb, hb);

    // CSR build + slot-ordered edge data
    hipMemsetAsync(deg, 0, (size_t)NNODES * 4, stream);
    deg_k<<<(NEDGES + 255) / 256, 256, 0, stream>>>(ei, deg);
    const int NB = (NNODES + 255) / 256;
    scan1_k<<<NB, 256, 0, stream>>>(deg, partial, btot);
    scan2_k<<<1, 256, 0, stream>>>(btot, NB);
    scan3_k<<<NB, 256, 0, stream>>>(deg, partial, btot, row_ptr, cursor);
    fill_k<<<(NEDGES + 255) / 256, 256, 0, stream>>>(ei, cursor, eid);
    esort_k<<<(NEDGES + 15) / 16, 256, 0, stream>>>(eattr, ei, eid, eattr_s, srcs);

    const int GG = (NNODES + 127) / 128;
    for (int l = 0; l < L; ++l) {
        agg_k<<<(NNODES + 15) / 16, 256, 0, stream>>>(
            hb, eattr_s, srcs, row_ptr, ew, eb, zb);
        gemm_k<true, false><<<GG, 256, 0, stream>>>(
            zb, wT + (size_t)l * 65536, b1 + l * HID, z1b, nullptr, NNODES);
        hipMemsetAsync(stats, 0, 512 * 4, stream);
        gemm_k<false, true><<<GG, 256, 0, stream>>>(
            z1b, wT + (size_t)(4 + l) * 65536, b2 + l * HID, zb, stats, NNODES);
        bn_relu_k<<<(int)(NH / 1024), 256, 0, stream>>>(
            zb, hb, stats, gam + l * HID, bet + l * HID);
    }

    hipMemsetAsync(g, 0, (size_t)NGRAPHS * HID * 4, stream);
    pool_k<<<(NNODES + PNB - 1) / PNB, 256, 0, stream>>>(hb, batch, g);
    head_k<<<NGRAPHS, 128, 0, stream>>>(g, hw1, hb1, hw2, hb2, out);
}

// Round 4
// 1145.866 us; speedup vs baseline: 1.4340x; 1.4340x over previous
//
#include <hip/hip_runtime.h>
#include <hip/hip_bf16.h>

#define HID     256
#define NNODES  50000
#define NEDGES  300000
#define NGRAPHS 128
#define L       4

typedef __attribute__((ext_vector_type(8))) short bf16x8;
typedef __attribute__((ext_vector_type(4))) float f32x4;
typedef __attribute__((ext_vector_type(4))) unsigned short u16x4;

static __device__ __forceinline__ float b2f(unsigned short s) {
    union { unsigned u; float f; } v;
    v.u = ((unsigned)s) << 16;
    return v.f;
}
static __device__ __forceinline__ short f2b(float f) {
    __hip_bfloat16 h = __float2bfloat16(f);
    return *reinterpret_cast<short*>(&h);
}

// ------------------------------------------------ weight convert + transpose
__global__ void wconv_k(const float* __restrict__ w, short* __restrict__ wT) {
    int m = blockIdx.y, n = blockIdx.x, k = threadIdx.x;
    wT[(size_t)m * 65536 + n * 256 + k] = f2b(w[(size_t)m * 65536 + k * 256 + n]);
}

// ---------------------------------------------------------------- node embed
__global__ void node_embed_k(const float* __restrict__ x,
                             const float* __restrict__ w,
                             const float* __restrict__ b,
                             short* __restrict__ hb) {
    int n = blockIdx.x;
    int j = threadIdx.x;
    __shared__ float xr[32];
    if (j < 32) xr[j] = x[n * 32 + j];
    __syncthreads();
    float acc = b[j];
#pragma unroll
    for (int k = 0; k < 32; ++k) acc = fmaf(xr[k], w[k * HID + j], acc);
    hb[(size_t)n * HID + j] = f2b(acc);
}

// ------------------------------------------------------------- CSR building
__global__ void deg_k(const int* __restrict__ ei, int* __restrict__ deg) {
    int e = blockIdx.x * 256 + threadIdx.x;
    if (e < NEDGES) atomicAdd(&deg[ei[NEDGES + e]], 1);
}

__global__ void scan1_k(const int* __restrict__ deg, int* __restrict__ partial,
                        int* __restrict__ btot) {
    __shared__ int s[256];
    int t = threadIdx.x;
    int gi = blockIdx.x * 256 + t;
    s[t] = (gi < NNODES) ? deg[gi] : 0;
    __syncthreads();
    for (int off = 1; off < 256; off <<= 1) {
        int u = (t >= off) ? s[t - off] : 0;
        __syncthreads();
        s[t] += u;
        __syncthreads();
    }
    if (gi < NNODES) partial[gi] = s[t];
    if (t == 255) btot[blockIdx.x] = s[255];
}

__global__ void scan2_k(int* __restrict__ btot, int nb) {
    __shared__ int s[256];
    int t = threadIdx.x;
    s[t] = (t < nb) ? btot[t] : 0;
    __syncthreads();
    for (int off = 1; off < 256; off <<= 1) {
        int u = (t >= off) ? s[t - off] : 0;
        __syncthreads();
        s[t] += u;
        __syncthreads();
    }
    btot[t] = s[t];
}

__global__ void scan3_k(const int* __restrict__ deg, const int* __restrict__ partial,
                        const int* __restrict__ btot, int* __restrict__ row_ptr,
                        int* __restrict__ cursor) {
    int gi = blockIdx.x * 256 + threadIdx.x;
    if (gi >= NNODES) return;
    int b = blockIdx.x;
    int incl = partial[gi] + (b ? btot[b - 1] : 0);
    int start = incl - deg[gi];
    row_ptr[gi] = start;
    cursor[gi] = start;
    if (gi == NNODES - 1) row_ptr[NNODES] = incl;
}

__global__ void fill_k(const int* __restrict__ ei, int* __restrict__ cursor,
                       int* __restrict__ eid) {
    int e = blockIdx.x * 256 + threadIdx.x;
    if (e < NEDGES) {
        int d = ei[NEDGES + e];
        int pos = atomicAdd(&cursor[d], 1);
        eid[pos] = e;
    }
}

// --------------------------------------- permute eattr/src into CSR slot order
__global__ void esort_k(const float* __restrict__ eattr, const int* __restrict__ ei,
                        const int* __restrict__ eid, float* __restrict__ eattr_s,
                        int* __restrict__ srcs) {
    int t = blockIdx.x * 16 + (threadIdx.x >> 4);
    int k = threadIdx.x & 15;
    if (t < NEDGES) {
        int e = eid[t];
        eattr_s[(size_t)t * 16 + k] = eattr[(size_t)e * 16 + k];
        if (k == 0) srcs[t] = ei[e];
    }
}

// ------------------------------------------------- CSR aggregate, wave-per-node
#define AGG_NPW 4
__global__ __launch_bounds__(256) void agg_k(
    const short* __restrict__ hb, const float* __restrict__ eattr_s,
    const int* __restrict__ srcs, const int* __restrict__ row_ptr,
    const float* __restrict__ ew, const float* __restrict__ ebias,
    short* __restrict__ zb) {
    int lane = threadIdx.x & 63, wv = threadIdx.x >> 6;
    int c = lane * 4;
    float ewv[16][4];
#pragma unroll
    for (int k = 0; k < 16; ++k) {
        float4 v = *reinterpret_cast<const float4*>(ew + k * 256 + c);
        ewv[k][0] = v.x; ewv[k][1] = v.y; ewv[k][2] = v.z; ewv[k][3] = v.w;
    }
    float4 ebv = *reinterpret_cast<const float4*>(ebias + c);
    float eb0 = ebv.x, eb1 = ebv.y, eb2 = ebv.z, eb3 = ebv.w;

    int n0 = (blockIdx.x * 4 + wv) * AGG_NPW;
    int n1 = min(n0 + AGG_NPW, NNODES);
    for (int n = n0; n < n1; ++n) {
        u16x4 h4 = *reinterpret_cast<const u16x4*>(hb + (size_t)n * HID + c);
        float acc[4];
#pragma unroll
        for (int i = 0; i < 4; ++i) acc[i] = b2f(h4[i]);
        int beg = row_ptr[n], end = row_ptr[n + 1];
        for (int t = beg; t < end; ++t) {
            int s = srcs[t];
            const float4* ep = reinterpret_cast<const float4*>(eattr_s + (size_t)t * 16);
            float4 q0 = ep[0], q1 = ep[1], q2 = ep[2], q3 = ep[3];
            u16x4 hs = *reinterpret_cast<const u16x4*>(hb + (size_t)s * HID + c);
            float m[4] = { eb0 + b2f(hs[0]), eb1 + b2f(hs[1]),
                           eb2 + b2f(hs[2]), eb3 + b2f(hs[3]) };
            float ek[16] = { q0.x, q0.y, q0.z, q0.w, q1.x, q1.y, q1.z, q1.w,
                             q2.x, q2.y, q2.z, q2.w, q3.x, q3.y, q3.z, q3.w };
#pragma unroll
            for (int k = 0; k < 16; ++k)
#pragma unroll
                for (int i = 0; i < 4; ++i) m[i] = fmaf(ek[k], ewv[k][i], m[i]);
#pragma unroll
            for (int i = 0; i < 4; ++i) acc[i] += fmaxf(m[i], 0.f);
        }
        u16x4 o;
#pragma unroll
        for (int i = 0; i < 4; ++i) o[i] = (unsigned short)f2b(acc[i]);
        *reinterpret_cast<u16x4*>(zb + (size_t)n * HID + c) = o;
    }
}

// ----------------------------------------------------------- bf16 MFMA GEMM
// C[M,256] = act(A@W + bias). BM=256 (4 waves x 64 rows), BN=64, K=256.
// B panel (64x256 bf16 = 32KB) staged once in LDS with XOR swizzle
// (byte ^= (n&7)<<4) so ds_read_b128 of B fragments is bank-balanced.
// Main loop: depth-1 A prefetch from global, 4 ds_read + 16 MFMA per k-step.
template <bool RELU, bool STATS>
__global__ __launch_bounds__(256, 3) void gemm_k(const short* __restrict__ A,
                                                 const short* __restrict__ wT,
                                                 const float* __restrict__ bias,
                                                 short* __restrict__ C,
                                                 float* __restrict__ stats, int M) {
    __shared__ short Bs[64 * 256]; // 32KB
    char* BsB = (char*)Bs;
    int wv = threadIdx.x >> 6, lane = threadIdx.x & 63;
    int lr = lane & 15, lg = lane >> 4;
    int c0 = blockIdx.y * 64;
    int bm = blockIdx.x * 256;
    int r0 = bm + wv * 64;

    // ---- stage B panel into LDS (swizzled write address)
    const char* panel = (const char*)(wT + (size_t)c0 * 256);
    {
        float4 v[4];
#pragma unroll
        for (int it = 0; it < 4; ++it)
            v[it] = *reinterpret_cast<const float4*>(panel + (threadIdx.x + it * 256) * 16);
#pragma unroll
        for (int it = 0; it < 4; ++it) {
            int o = (threadIdx.x + it * 256) * 16;
            int n = o >> 9;
            *reinterpret_cast<float4*>(BsB + (o ^ ((n & 7) << 4))) = v[it];
        }
        float4 v2[4];
#pragma unroll
        for (int it = 4; it < 8; ++it)
            v2[it - 4] = *reinterpret_cast<const float4*>(panel + (threadIdx.x + it * 256) * 16);
#pragma unroll
        for (int it = 4; it < 8; ++it) {
            int o = (threadIdx.x + it * 256) * 16;
            int n = o >> 9;
            *reinterpret_cast<float4*>(BsB + (o ^ ((n & 7) << 4))) = v2[it - 4];
        }
    }

    // A row pointers (4 row-fragments per wave)
    const short* pA[4];
    bool gok[4];
#pragma unroll
    for (int f = 0; f < 4; ++f) {
        int r = r0 + f * 16 + lr;
        gok[f] = r < M;
        pA[f] = A + (size_t)r * 256 + lg * 8;
    }

    f32x4 acc[4][4] = {};
    bf16x8 aCur[4] = {}, aNxt[4] = {};
#pragma unroll
    for (int f = 0; f < 4; ++f)
        if (gok[f]) aCur[f] = *reinterpret_cast<const bf16x8*>(pA[f]);

    __syncthreads();

    for (int k0 = 0; k0 < 256; k0 += 32) {
        if (k0 < 224) {
#pragma unroll
            for (int f = 0; f < 4; ++f)
                if (gok[f]) aNxt[f] = *reinterpret_cast<const bf16x8*>(pA[f] + k0 + 32);
        }
#pragma unroll
        for (int cc = 0; cc < 4; ++cc) {
            int n = cc * 16 + lr;
            int kb = k0 * 2 + lg * 16;
            bf16x8 b = *reinterpret_cast<const bf16x8*>(
                BsB + ((n * 512 + (kb ^ ((n & 7) << 4)))));
#pragma unroll
            for (int f = 0; f < 4; ++f)
                acc[f][cc] = __builtin_amdgcn_mfma_f32_16x16x32_bf16(aCur[f], b, acc[f][cc], 0, 0, 0);
        }
#pragma unroll
        for (int f = 0; f < 4; ++f) aCur[f] = aNxt[f];
    }

#pragma unroll
    for (int cc = 0; cc < 4; ++cc) {
        int col = c0 + cc * 16 + lr;
        float bi = bias[col];
        float s = 0.f, ss = 0.f;
#pragma unroll
        for (int f = 0; f < 4; ++f)
#pragma unroll
            for (int i = 0; i < 4; ++i) {
                int row = r0 + f * 16 + lg * 4 + i;
                if (row < M) {
                    float v = acc[f][cc][i] + bi;
                    if (RELU) v = fmaxf(v, 0.f);
                    C[(size_t)row * 256 + col] = f2b(v);
                    if (STATS) { s += v; ss = fmaf(v, v, ss); }
                }
            }
        if (STATS) {
            s  += __shfl_xor(s, 16);  ss += __shfl_xor(ss, 16);
            s  += __shfl_xor(s, 32);  ss += __shfl_xor(ss, 32);
            if (lg == 0) {
                atomicAdd(&stats[col], s);
                atomicAdd(&stats[HID + col], ss);
            }
        }
    }
}

// ------------------------------------------------------- BN normalize+relu
__global__ void bn_relu_k(const short* __restrict__ z, short* __restrict__ hb,
                          const float* __restrict__ stats,
                          const float* __restrict__ gamma,
                          const float* __restrict__ beta) {
    int gidx = blockIdx.x * 256 + threadIdx.x;
    int base = gidx * 4;
    int j = base & 255;
    u16x4 z4 = *reinterpret_cast<const u16x4*>(z + base);
    u16x4 o;
#pragma unroll
    for (int i = 0; i < 4; ++i) {
        float mu  = stats[j + i] * (1.f / NNODES);
        float var = stats[HID + j + i] * (1.f / NNODES) - mu * mu;
        float inv = rsqrtf(var + 1e-5f);
        float v = (b2f(z4[i]) - mu) * inv * gamma[j + i] + beta[j + i];
        o[i] = (unsigned short)f2b(fmaxf(v, 0.f));
    }
    *reinterpret_cast<u16x4*>(hb + base) = o;
}

// ------------------------------------------------------------------ pool
#define PNB 64
__global__ void pool_k(const short* __restrict__ hb, const int* __restrict__ batch,
                       float* __restrict__ g) {
    int j = threadIdx.x;
    int n0 = blockIdx.x * PNB;
    int n1 = min(n0 + PNB, NNODES);
    int cur = batch[n0];
    float acc = 0.f;
    for (int n = n0; n < n1; ++n) {
        int b = batch[n];
        if (b != cur) {
            atomicAdd(&g[(size_t)cur * HID + j], acc);
            acc = 0.f; cur = b;
        }
        acc += b2f((unsigned short)hb[(size_t)n * HID + j]);
    }
    atomicAdd(&g[(size_t)cur * HID + j], acc);
}

// ------------------------------------------------------------------ head
__global__ void head_k(const float* __restrict__ g, const float* __restrict__ w1,
                       const float* __restrict__ b1, const float* __restrict__ w2,
                       const float* __restrict__ b2, float* __restrict__ out) {
    int gi = blockIdx.x;
    int j  = threadIdx.x;
    __shared__ float gr[256];
    __shared__ float hid[128];
    gr[j]       = g[gi * 256 + j];
    gr[j + 128] = g[gi * 256 + 128 + j];
    __syncthreads();
    float acc = b1[j];
    for (int k = 0; k < 256; ++k) acc = fmaf(gr[k], w1[k * 128 + j], acc);
    hid[j] = fmaxf(acc, 0.f);
    __syncthreads();
    if (j < 12) {
        float o = b2[j];
#pragma unroll
        for (int k = 0; k < 128; ++k) o = fmaf(hid[k], w2[k * 12 + j], o);
        out[gi * 12 + j] = o;
    }
}

// ---------------------------------------------------------------- launch
extern "C" void kernel_launch(void* const* d_in, const int* in_sizes, int n_in,
                              void* d_out, int out_size, void* d_ws, size_t ws_size,
                              hipStream_t stream) {
    const float* x     = (const float*)d_in[0];
    const int*   ei    = (const int*)d_in[1];
    const int*   batch = (const int*)d_in[2];
    const float* eattr = (const float*)d_in[3];
    const float* nw    = (const float*)d_in[4];
    const float* nb    = (const float*)d_in[5];
    const float* ew    = (const float*)d_in[6];
    const float* eb    = (const float*)d_in[7];
    const float* w1    = (const float*)d_in[8];
    const float* b1    = (const float*)d_in[9];
    const float* w2    = (const float*)d_in[10];
    const float* b2    = (const float*)d_in[11];
    const float* gam   = (const float*)d_in[12];
    const float* bet   = (const float*)d_in[13];
    const float* hw1   = (const float*)d_in[14];
    const float* hb1   = (const float*)d_in[15];
    const float* hw2   = (const float*)d_in[16];
    const float* hb2   = (const float*)d_in[17];
    float* out = (float*)d_out;

    const size_t NH = (size_t)NNODES * HID;
    size_t off = 0;
    char* base = (char*)d_ws;
    auto alloc = [&](size_t bytes) -> void* {
        void* p = base + off;
        off += (bytes + 255) & ~(size_t)255;
        return p;
    };
    short* hb      = (short*)alloc(NH * 2);
    short* zb      = (short*)alloc(NH * 2);
    short* z1b     = (short*)alloc(NH * 2);
    short* wT      = (short*)alloc(8 * 65536 * 2);
    float* eattr_s = (float*)alloc((size_t)NEDGES * 16 * 4);
    int*   srcs    = (int*)alloc((size_t)NEDGES * 4);
    float* stats   = (float*)alloc(512 * 4);
    float* g       = (float*)alloc((size_t)NGRAPHS * HID * 4);
    int*   deg     = (int*)alloc((size_t)NNODES * 4);
    int*   partial = (int*)alloc((size_t)NNODES * 4);
    int*   btot    = (int*)alloc(256 * 4);
    int*   row_ptr = (int*)alloc((size_t)(NNODES + 1) * 4);
    int*   cursor  = (int*)alloc((size_t)NNODES * 4);
    int*   eid     = (int*)alloc((size_t)NEDGES * 4);

    wconv_k<<<dim3(256, 4), 256, 0, stream>>>(w1, wT);
    wconv_k<<<dim3(256, 4), 256, 0, stream>>>(w2, wT + 4 * 65536);
    node_embed_k<<<NNODES, 256, 0, stream>>>(x, nw, nb, hb);

    hipMemsetAsync(deg, 0, (size_t)NNODES * 4, stream);
    deg_k<<<(NEDGES + 255) / 256, 256, 0, stream>>>(ei, deg);
    const int NB = (NNODES + 255) / 256;
    scan1_k<<<NB, 256, 0, stream>>>(deg, partial, btot);
    scan2_k<<<1, 256, 0, stream>>>(btot, NB);
    scan3_k<<<NB, 256, 0, stream>>>(deg, partial, btot, row_ptr, cursor);
    fill_k<<<(NEDGES + 255) / 256, 256, 0, stream>>>(ei, cursor, eid);
    esort_k<<<(NEDGES + 15) / 16, 256, 0, stream>>>(eattr, ei, eid, eattr_s, srcs);

    dim3 ggrid((NNODES + 255) / 256, 4);
    for (int l = 0; l < L; ++l) {
        agg_k<<<(NNODES + 15) / 16, 256, 0, stream>>>(
            hb, eattr_s, srcs, row_ptr, ew, eb, zb);
        gemm_k<true, false><<<ggrid, 256, 0, stream>>>(
            zb, wT + (size_t)l * 65536, b1 + l * HID, z1b, nullptr, NNODES);
        hipMemsetAsync(stats, 0, 512 * 4, stream);
        gemm_k<false, true><<<ggrid, 256, 0, stream>>>(
            z1b, wT + (size_t)(4 + l) * 65536, b2 + l * HID, zb, stats, NNODES);
        bn_relu_k<<<(int)(NH / 1024), 256, 0, stream>>>(
            zb, hb, stats, gam + l * HID, bet + l * HID);
    }

    hipMemsetAsync(g, 0, (size_t)NGRAPHS * HID * 4, stream);
    pool_k<<<(NNODES + PNB - 1) / PNB, 256, 0, stream>>>(hb, batch, g);
    head_k<<<NGRAPHS, 128, 0, stream>>>(g, hw1, hb1, hw2, hb2, out);
}

// Round 5
// 987.959 us; speedup vs baseline: 1.6632x; 1.1598x over previous
//
#include <hip/hip_runtime.h>
#include <hip/hip_bf16.h>

#define HID     256
#define NNODES  50000
#define NEDGES  300000
#define NGRAPHS 128
#define L       4

typedef __attribute__((ext_vector_type(8))) short bf16x8;
typedef __attribute__((ext_vector_type(4))) float f32x4;
typedef __attribute__((ext_vector_type(4))) unsigned short u16x4;

static __device__ __forceinline__ float b2f(unsigned short s) {
    union { unsigned u; float f; } v;
    v.u = ((unsigned)s) << 16;
    return v.f;
}
static __device__ __forceinline__ short f2b(float f) {
    __hip_bfloat16 h = __float2bfloat16(f);
    return *reinterpret_cast<short*>(&h);
}

// ------------------------------------------------ weight convert + transpose
__global__ void wconv_k(const float* __restrict__ w, short* __restrict__ wT) {
    int m = blockIdx.y, n = blockIdx.x, k = threadIdx.x;
    wT[(size_t)m * 65536 + n * 256 + k] = f2b(w[(size_t)m * 65536 + k * 256 + n]);
}

// ---------------------------------------------------------------- node embed
__global__ void node_embed_k(const float* __restrict__ x,
                             const float* __restrict__ w,
                             const float* __restrict__ b,
                             short* __restrict__ hb) {
    int n = blockIdx.x;
    int j = threadIdx.x;
    __shared__ float xr[32];
    if (j < 32) xr[j] = x[n * 32 + j];
    __syncthreads();
    float acc = b[j];
#pragma unroll
    for (int k = 0; k < 32; ++k) acc = fmaf(xr[k], w[k * HID + j], acc);
    hb[(size_t)n * HID + j] = f2b(acc);
}

// ------------------------------------------------------------- CSR building
__global__ void deg_k(const int* __restrict__ ei, int* __restrict__ deg) {
    int e = blockIdx.x * 256 + threadIdx.x;
    if (e < NEDGES) atomicAdd(&deg[ei[NEDGES + e]], 1);
}

__global__ void scan1_k(const int* __restrict__ deg, int* __restrict__ partial,
                        int* __restrict__ btot) {
    __shared__ int s[256];
    int t = threadIdx.x;
    int gi = blockIdx.x * 256 + t;
    s[t] = (gi < NNODES) ? deg[gi] : 0;
    __syncthreads();
    for (int off = 1; off < 256; off <<= 1) {
        int u = (t >= off) ? s[t - off] : 0;
        __syncthreads();
        s[t] += u;
        __syncthreads();
    }
    if (gi < NNODES) partial[gi] = s[t];
    if (t == 255) btot[blockIdx.x] = s[255];
}

__global__ void scan2_k(int* __restrict__ btot, int nb) {
    __shared__ int s[256];
    int t = threadIdx.x;
    s[t] = (t < nb) ? btot[t] : 0;
    __syncthreads();
    for (int off = 1; off < 256; off <<= 1) {
        int u = (t >= off) ? s[t - off] : 0;
        __syncthreads();
        s[t] += u;
        __syncthreads();
    }
    btot[t] = s[t];
}

__global__ void scan3_k(const int* __restrict__ deg, const int* __restrict__ partial,
                        const int* __restrict__ btot, int* __restrict__ row_ptr,
                        int* __restrict__ cursor) {
    int gi = blockIdx.x * 256 + threadIdx.x;
    if (gi >= NNODES) return;
    int b = blockIdx.x;
    int incl = partial[gi] + (b ? btot[b - 1] : 0);
    int start = incl - deg[gi];
    row_ptr[gi] = start;
    cursor[gi] = start;
    if (gi == NNODES - 1) row_ptr[NNODES] = incl;
}

__global__ void fill_k(const int* __restrict__ ei, int* __restrict__ cursor,
                       int* __restrict__ eid) {
    int e = blockIdx.x * 256 + threadIdx.x;
    if (e < NEDGES) {
        int d = ei[NEDGES + e];
        int pos = atomicAdd(&cursor[d], 1);
        eid[pos] = e;
    }
}

// ---------------- one-time: ea_s[t] = bf16(eattr[eid[t]] @ ew + eb), srcs[t]
// ea is layer-invariant in the reference -> compute once, slot-ordered.
#define EA_EPW 8
__global__ __launch_bounds__(256) void ea_k(const float* __restrict__ eattr,
                                            const int* __restrict__ ei,
                                            const int* __restrict__ eid,
                                            const float* __restrict__ ew,
                                            const float* __restrict__ ebias,
                                            short* __restrict__ ea_s,
                                            int* __restrict__ srcs) {
    int lane = threadIdx.x & 63, wv = threadIdx.x >> 6;
    int c = lane * 4;
    float ewv[16][4];
#pragma unroll
    for (int k = 0; k < 16; ++k) {
        float4 v = *reinterpret_cast<const float4*>(ew + k * 256 + c);
        ewv[k][0] = v.x; ewv[k][1] = v.y; ewv[k][2] = v.z; ewv[k][3] = v.w;
    }
    float4 ebv = *reinterpret_cast<const float4*>(ebias + c);

    int t0 = (blockIdx.x * 4 + wv) * EA_EPW;
    int t1 = min(t0 + EA_EPW, NEDGES);
    for (int t = t0; t < t1; ++t) {
        int e = eid[t];
        const float4* ep = reinterpret_cast<const float4*>(eattr + (size_t)e * 16);
        float4 q0 = ep[0], q1 = ep[1], q2 = ep[2], q3 = ep[3];
        float m[4] = { ebv.x, ebv.y, ebv.z, ebv.w };
        float ek[16] = { q0.x, q0.y, q0.z, q0.w, q1.x, q1.y, q1.z, q1.w,
                         q2.x, q2.y, q2.z, q2.w, q3.x, q3.y, q3.z, q3.w };
#pragma unroll
        for (int k = 0; k < 16; ++k)
#pragma unroll
            for (int i = 0; i < 4; ++i) m[i] = fmaf(ek[k], ewv[k][i], m[i]);
        u16x4 o;
#pragma unroll
        for (int i = 0; i < 4; ++i) o[i] = (unsigned short)f2b(m[i]);
        *reinterpret_cast<u16x4*>(ea_s + (size_t)t * HID + c) = o;
        if (lane == 0) srcs[t] = ei[e];
    }
}

// ------------------------------------------------- CSR aggregate, wave-per-node
// zb[n] = hb[n] + sum_t relu(hb[srcs[t]] + ea_s[t]);  unroll x4 for MLP.
#define AGG_NPW 4
__global__ __launch_bounds__(256) void agg_k(
    const short* __restrict__ hb, const short* __restrict__ ea_s,
    const int* __restrict__ srcs, const int* __restrict__ row_ptr,
    short* __restrict__ zb) {
    int lane = threadIdx.x & 63, wv = threadIdx.x >> 6;
    int c = lane * 4;
    int n0 = (blockIdx.x * 4 + wv) * AGG_NPW;
    int n1 = min(n0 + AGG_NPW, NNODES);
    for (int n = n0; n < n1; ++n) {
        u16x4 h4 = *reinterpret_cast<const u16x4*>(hb + (size_t)n * HID + c);
        float acc0 = b2f(h4[0]), acc1 = b2f(h4[1]), acc2 = b2f(h4[2]), acc3 = b2f(h4[3]);
        int beg = row_ptr[n], end = row_ptr[n + 1];
        int t = beg;
        for (; t + 4 <= end; t += 4) {
            int s0 = srcs[t], s1 = srcs[t + 1], s2 = srcs[t + 2], s3 = srcs[t + 3];
            u16x4 e0 = *reinterpret_cast<const u16x4*>(ea_s + (size_t)(t + 0) * HID + c);
            u16x4 e1 = *reinterpret_cast<const u16x4*>(ea_s + (size_t)(t + 1) * HID + c);
            u16x4 e2 = *reinterpret_cast<const u16x4*>(ea_s + (size_t)(t + 2) * HID + c);
            u16x4 e3 = *reinterpret_cast<const u16x4*>(ea_s + (size_t)(t + 3) * HID + c);
            u16x4 g0 = *reinterpret_cast<const u16x4*>(hb + (size_t)s0 * HID + c);
            u16x4 g1 = *reinterpret_cast<const u16x4*>(hb + (size_t)s1 * HID + c);
            u16x4 g2 = *reinterpret_cast<const u16x4*>(hb + (size_t)s2 * HID + c);
            u16x4 g3 = *reinterpret_cast<const u16x4*>(hb + (size_t)s3 * HID + c);
            acc0 += fmaxf(b2f(e0[0]) + b2f(g0[0]), 0.f) + fmaxf(b2f(e1[0]) + b2f(g1[0]), 0.f)
                  + fmaxf(b2f(e2[0]) + b2f(g2[0]), 0.f) + fmaxf(b2f(e3[0]) + b2f(g3[0]), 0.f);
            acc1 += fmaxf(b2f(e0[1]) + b2f(g0[1]), 0.f) + fmaxf(b2f(e1[1]) + b2f(g1[1]), 0.f)
                  + fmaxf(b2f(e2[1]) + b2f(g2[1]), 0.f) + fmaxf(b2f(e3[1]) + b2f(g3[1]), 0.f);
            acc2 += fmaxf(b2f(e0[2]) + b2f(g0[2]), 0.f) + fmaxf(b2f(e1[2]) + b2f(g1[2]), 0.f)
                  + fmaxf(b2f(e2[2]) + b2f(g2[2]), 0.f) + fmaxf(b2f(e3[2]) + b2f(g3[2]), 0.f);
            acc3 += fmaxf(b2f(e0[3]) + b2f(g0[3]), 0.f) + fmaxf(b2f(e1[3]) + b2f(g1[3]), 0.f)
                  + fmaxf(b2f(e2[3]) + b2f(g2[3]), 0.f) + fmaxf(b2f(e3[3]) + b2f(g3[3]), 0.f);
        }
        for (; t < end; ++t) {
            int s = srcs[t];
            u16x4 e0 = *reinterpret_cast<const u16x4*>(ea_s + (size_t)t * HID + c);
            u16x4 g0 = *reinterpret_cast<const u16x4*>(hb + (size_t)s * HID + c);
            acc0 += fmaxf(b2f(e0[0]) + b2f(g0[0]), 0.f);
            acc1 += fmaxf(b2f(e0[1]) + b2f(g0[1]), 0.f);
            acc2 += fmaxf(b2f(e0[2]) + b2f(g0[2]), 0.f);
            acc3 += fmaxf(b2f(e0[3]) + b2f(g0[3]), 0.f);
        }
        u16x4 o;
        o[0] = (unsigned short)f2b(acc0);
        o[1] = (unsigned short)f2b(acc1);
        o[2] = (unsigned short)f2b(acc2);
        o[3] = (unsigned short)f2b(acc3);
        *reinterpret_cast<u16x4*>(zb + (size_t)n * HID + c) = o;
    }
}

// ----------------------------------------------------------- bf16 MFMA GEMM
// C[M,256] = act(A@W + bias). BM=256 (4 waves x 64 rows), BN=64, K=256.
// B panel (64x256 bf16 = 32KB) in LDS, XOR-swizzled; depth-1 A prefetch.
template <bool RELU, bool STATS>
__global__ __launch_bounds__(256, 3) void gemm_k(const short* __restrict__ A,
                                                 const short* __restrict__ wT,
                                                 const float* __restrict__ bias,
                                                 short* __restrict__ C,
                                                 float* __restrict__ stats, int M) {
    __shared__ short Bs[64 * 256]; // 32KB
    char* BsB = (char*)Bs;
    int wv = threadIdx.x >> 6, lane = threadIdx.x & 63;
    int lr = lane & 15, lg = lane >> 4;
    int c0 = blockIdx.y * 64;
    int bm = blockIdx.x * 256;
    int r0 = bm + wv * 64;

    const char* panel = (const char*)(wT + (size_t)c0 * 256);
    {
        float4 v[4];
#pragma unroll
        for (int it = 0; it < 4; ++it)
            v[it] = *reinterpret_cast<const float4*>(panel + (threadIdx.x + it * 256) * 16);
#pragma unroll
        for (int it = 0; it < 4; ++it) {
            int o = (threadIdx.x + it * 256) * 16;
            int n = o >> 9;
            *reinterpret_cast<float4*>(BsB + (o ^ ((n & 7) << 4))) = v[it];
        }
        float4 v2[4];
#pragma unroll
        for (int it = 4; it < 8; ++it)
            v2[it - 4] = *reinterpret_cast<const float4*>(panel + (threadIdx.x + it * 256) * 16);
#pragma unroll
        for (int it = 4; it < 8; ++it) {
            int o = (threadIdx.x + it * 256) * 16;
            int n = o >> 9;
            *reinterpret_cast<float4*>(BsB + (o ^ ((n & 7) << 4))) = v2[it - 4];
        }
    }

    const short* pA[4];
    bool gok[4];
#pragma unroll
    for (int f = 0; f < 4; ++f) {
        int r = r0 + f * 16 + lr;
        gok[f] = r < M;
        pA[f] = A + (size_t)r * 256 + lg * 8;
    }

    f32x4 acc[4][4] = {};
    bf16x8 aCur[4] = {}, aNxt[4] = {};
#pragma unroll
    for (int f = 0; f < 4; ++f)
        if (gok[f]) aCur[f] = *reinterpret_cast<const bf16x8*>(pA[f]);

    __syncthreads();

    for (int k0 = 0; k0 < 256; k0 += 32) {
        if (k0 < 224) {
#pragma unroll
            for (int f = 0; f < 4; ++f)
                if (gok[f]) aNxt[f] = *reinterpret_cast<const bf16x8*>(pA[f] + k0 + 32);
        }
#pragma unroll
        for (int cc = 0; cc < 4; ++cc) {
            int n = cc * 16 + lr;
            int kb = k0 * 2 + lg * 16;
            bf16x8 b = *reinterpret_cast<const bf16x8*>(
                BsB + ((n * 512 + (kb ^ ((n & 7) << 4)))));
#pragma unroll
            for (int f = 0; f < 4; ++f)
                acc[f][cc] = __builtin_amdgcn_mfma_f32_16x16x32_bf16(aCur[f], b, acc[f][cc], 0, 0, 0);
        }
#pragma unroll
        for (int f = 0; f < 4; ++f) aCur[f] = aNxt[f];
    }

#pragma unroll
    for (int cc = 0; cc < 4; ++cc) {
        int col = c0 + cc * 16 + lr;
        float bi = bias[col];
        float s = 0.f, ss = 0.f;
#pragma unroll
        for (int f = 0; f < 4; ++f)
#pragma unroll
            for (int i = 0; i < 4; ++i) {
                int row = r0 + f * 16 + lg * 4 + i;
                if (row < M) {
                    float v = acc[f][cc][i] + bi;
                    if (RELU) v = fmaxf(v, 0.f);
                    C[(size_t)row * 256 + col] = f2b(v);
                    if (STATS) { s += v; ss = fmaf(v, v, ss); }
                }
            }
        if (STATS) {
            s  += __shfl_xor(s, 16);  ss += __shfl_xor(ss, 16);
            s  += __shfl_xor(s, 32);  ss += __shfl_xor(ss, 32);
            if (lg == 0) {
                atomicAdd(&stats[col], s);
                atomicAdd(&stats[HID + col], ss);
            }
        }
    }
}

// ------------------------------------------------------- BN normalize+relu
__global__ void bn_relu_k(const short* __restrict__ z, short* __restrict__ hb,
                          const float* __restrict__ stats,
                          const float* __restrict__ gamma,
                          const float* __restrict__ beta) {
    int gidx = blockIdx.x * 256 + threadIdx.x;
    int base = gidx * 4;
    int j = base & 255;
    u16x4 z4 = *reinterpret_cast<const u16x4*>(z + base);
    u16x4 o;
#pragma unroll
    for (int i = 0; i < 4; ++i) {
        float mu  = stats[j + i] * (1.f / NNODES);
        float var = stats[HID + j + i] * (1.f / NNODES) - mu * mu;
        float inv = rsqrtf(var + 1e-5f);
        float v = (b2f(z4[i]) - mu) * inv * gamma[j + i] + beta[j + i];
        o[i] = (unsigned short)f2b(fmaxf(v, 0.f));
    }
    *reinterpret_cast<u16x4*>(hb + base) = o;
}

// ------------------------------------------------------------------ pool
#define PNB 64
__global__ void pool_k(const short* __restrict__ hb, const int* __restrict__ batch,
                       float* __restrict__ g) {
    int j = threadIdx.x;
    int n0 = blockIdx.x * PNB;
    int n1 = min(n0 + PNB, NNODES);
    int cur = batch[n0];
    float acc = 0.f;
    for (int n = n0; n < n1; ++n) {
        int b = batch[n];
        if (b != cur) {
            atomicAdd(&g[(size_t)cur * HID + j], acc);
            acc = 0.f; cur = b;
        }
        acc += b2f((unsigned short)hb[(size_t)n * HID + j]);
    }
    atomicAdd(&g[(size_t)cur * HID + j], acc);
}

// ------------------------------------------------------------------ head
__global__ void head_k(const float* __restrict__ g, const float* __restrict__ w1,
                       const float* __restrict__ b1, const float* __restrict__ w2,
                       const float* __restrict__ b2, float* __restrict__ out) {
    int gi = blockIdx.x;
    int j  = threadIdx.x;
    __shared__ float gr[256];
    __shared__ float hid[128];
    gr[j]       = g[gi * 256 + j];
    gr[j + 128] = g[gi * 256 + 128 + j];
    __syncthreads();
    float acc = b1[j];
    for (int k = 0; k < 256; ++k) acc = fmaf(gr[k], w1[k * 128 + j], acc);
    hid[j] = fmaxf(acc, 0.f);
    __syncthreads();
    if (j < 12) {
        float o = b2[j];
#pragma unroll
        for (int k = 0; k < 128; ++k) o = fmaf(hid[k], w2[k * 12 + j], o);
        out[gi * 12 + j] = o;
    }
}

// ---------------------------------------------------------------- launch
extern "C" void kernel_launch(void* const* d_in, const int* in_sizes, int n_in,
                              void* d_out, int out_size, void* d_ws, size_t ws_size,
                              hipStream_t stream) {
    const float* x     = (const float*)d_in[0];
    const int*   ei    = (const int*)d_in[1];
    const int*   batch = (const int*)d_in[2];
    const float* eattr = (const float*)d_in[3];
    const float* nw    = (const float*)d_in[4];
    const float* nb    = (const float*)d_in[5];
    const float* ew    = (const float*)d_in[6];
    const float* eb    = (const float*)d_in[7];
    const float* w1    = (const float*)d_in[8];
    const float* b1    = (const float*)d_in[9];
    const float* w2    = (const float*)d_in[10];
    const float* b2    = (const float*)d_in[11];
    const float* gam   = (const float*)d_in[12];
    const float* bet   = (const float*)d_in[13];
    const float* hw1   = (const float*)d_in[14];
    const float* hb1   = (const float*)d_in[15];
    const float* hw2   = (const float*)d_in[16];
    const float* hb2   = (const float*)d_in[17];
    float* out = (float*)d_out;

    const size_t NH = (size_t)NNODES * HID;
    const size_t EH = (size_t)NEDGES * HID;
    size_t off = 0;
    char* base = (char*)d_ws;
    auto alloc = [&](size_t bytes) -> void* {
        void* p = base + off;
        off += (bytes + 255) & ~(size_t)255;
        return p;
    };
    short* hb      = (short*)alloc(NH * 2);
    short* zb      = (short*)alloc(NH * 2);
    short* z1b     = (short*)alloc(NH * 2);
    short* wT      = (short*)alloc(8 * 65536 * 2);
    short* ea_s    = (short*)alloc(EH * 2);       // 153.6 MB, layer-invariant
    int*   srcs    = (int*)alloc((size_t)NEDGES * 4);
    float* stats   = (float*)alloc(512 * 4);
    float* g       = (float*)alloc((size_t)NGRAPHS * HID * 4);
    int*   deg     = (int*)alloc((size_t)NNODES * 4);
    int*   partial = (int*)alloc((size_t)NNODES * 4);
    int*   btot    = (int*)alloc(256 * 4);
    int*   row_ptr = (int*)alloc((size_t)(NNODES + 1) * 4);
    int*   cursor  = (int*)alloc((size_t)NNODES * 4);
    int*   eid     = (int*)alloc((size_t)NEDGES * 4);

    wconv_k<<<dim3(256, 4), 256, 0, stream>>>(w1, wT);
    wconv_k<<<dim3(256, 4), 256, 0, stream>>>(w2, wT + 4 * 65536);
    node_embed_k<<<NNODES, 256, 0, stream>>>(x, nw, nb, hb);

    hipMemsetAsync(deg, 0, (size_t)NNODES * 4, stream);
    deg_k<<<(NEDGES + 255) / 256, 256, 0, stream>>>(ei, deg);
    const int NB = (NNODES + 255) / 256;
    scan1_k<<<NB, 256, 0, stream>>>(deg, partial, btot);
    scan2_k<<<1, 256, 0, stream>>>(btot, NB);
    scan3_k<<<NB, 256, 0, stream>>>(deg, partial, btot, row_ptr, cursor);
    fill_k<<<(NEDGES + 255) / 256, 256, 0, stream>>>(ei, cursor, eid);
    ea_k<<<(NEDGES + 4 * EA_EPW - 1) / (4 * EA_EPW), 256, 0, stream>>>(
        eattr, ei, eid, ew, eb, ea_s, srcs);

    dim3 ggrid((NNODES + 255) / 256, 4);
    for (int l = 0; l < L; ++l) {
        agg_k<<<(NNODES + 15) / 16, 256, 0, stream>>>(
            hb, ea_s, srcs, row_ptr, zb);
        gemm_k<true, false><<<ggrid, 256, 0, stream>>>(
            zb, wT + (size_t)l * 65536, b1 + l * HID, z1b, nullptr, NNODES);
        hipMemsetAsync(stats, 0, 512 * 4, stream);
        gemm_k<false, true><<<ggrid, 256, 0, stream>>>(
            z1b, wT + (size_t)(4 + l) * 65536, b2 + l * HID, zb, stats, NNODES);
        bn_relu_k<<<(int)(NH / 1024), 256, 0, stream>>>(
            zb, hb, stats, gam + l * HID, bet + l * HID);
    }

    hipMemsetAsync(g, 0, (size_t)NGRAPHS * HID * 4, stream);
    pool_k<<<(NNODES + PNB - 1) / PNB, 256, 0, stream>>>(hb, batch, g);
    head_k<<<NGRAPHS, 128, 0, stream>>>(g, hw1, hb1, hw2, hb2, out);
}

// Round 6
// 868.461 us; speedup vs baseline: 1.8920x; 1.1376x over previous
//
#include <hip/hip_runtime.h>
#include <hip/hip_bf16.h>

#define HID     256
#define NNODES  50000
#define NEDGES  300000
#define NGRAPHS 128
#define L       4

typedef __attribute__((ext_vector_type(8))) short bf16x8;
typedef __attribute__((ext_vector_type(4))) float f32x4;
typedef __attribute__((ext_vector_type(4))) unsigned short u16x4;

static __device__ __forceinline__ float b2f(unsigned short s) {
    union { unsigned u; float f; } v;
    v.u = ((unsigned)s) << 16;
    return v.f;
}
static __device__ __forceinline__ short f2b(float f) {
    __hip_bfloat16 h = __float2bfloat16(f);
    return *reinterpret_cast<short*>(&h);
}

// ------------------------------------------------ weight convert + transpose
__global__ void wconv_k(const float* __restrict__ w, short* __restrict__ wT) {
    int m = blockIdx.y, n = blockIdx.x, k = threadIdx.x;
    wT[(size_t)m * 65536 + n * 256 + k] = f2b(w[(size_t)m * 65536 + k * 256 + n]);
}

// ---------------------------------------------------------------- node embed
__global__ void node_embed_k(const float* __restrict__ x,
                             const float* __restrict__ w,
                             const float* __restrict__ b,
                             short* __restrict__ hb) {
    int n = blockIdx.x;
    int j = threadIdx.x;
    __shared__ float xr[32];
    if (j < 32) xr[j] = x[n * 32 + j];
    __syncthreads();
    float acc = b[j];
#pragma unroll
    for (int k = 0; k < 32; ++k) acc = fmaf(xr[k], w[k * HID + j], acc);
    hb[(size_t)n * HID + j] = f2b(acc);
}

// ------------------------------------------------------------- CSR building
__global__ void deg_k(const int* __restrict__ ei, int* __restrict__ deg) {
    int e = blockIdx.x * 256 + threadIdx.x;
    if (e < NEDGES) atomicAdd(&deg[ei[NEDGES + e]], 1);
}

__global__ void scan1_k(const int* __restrict__ deg, int* __restrict__ partial,
                        int* __restrict__ btot) {
    __shared__ int s[256];
    int t = threadIdx.x;
    int gi = blockIdx.x * 256 + t;
    s[t] = (gi < NNODES) ? deg[gi] : 0;
    __syncthreads();
    for (int off = 1; off < 256; off <<= 1) {
        int u = (t >= off) ? s[t - off] : 0;
        __syncthreads();
        s[t] += u;
        __syncthreads();
    }
    if (gi < NNODES) partial[gi] = s[t];
    if (t == 255) btot[blockIdx.x] = s[255];
}

__global__ void scan2_k(int* __restrict__ btot, int nb) {
    __shared__ int s[256];
    int t = threadIdx.x;
    s[t] = (t < nb) ? btot[t] : 0;
    __syncthreads();
    for (int off = 1; off < 256; off <<= 1) {
        int u = (t >= off) ? s[t - off] : 0;
        __syncthreads();
        s[t] += u;
        __syncthreads();
    }
    btot[t] = s[t];
}

__global__ void scan3_k(const int* __restrict__ deg, const int* __restrict__ partial,
                        const int* __restrict__ btot, int* __restrict__ row_ptr,
                        int* __restrict__ cursor) {
    int gi = blockIdx.x * 256 + threadIdx.x;
    if (gi >= NNODES) return;
    int b = blockIdx.x;
    int incl = partial[gi] + (b ? btot[b - 1] : 0);
    int start = incl - deg[gi];
    row_ptr[gi] = start;
    cursor[gi] = start;
    if (gi == NNODES - 1) row_ptr[NNODES] = incl;
}

__global__ void fill_k(const int* __restrict__ ei, int* __restrict__ cursor,
                       int* __restrict__ eid) {
    int e = blockIdx.x * 256 + threadIdx.x;
    if (e < NEDGES) {
        int d = ei[NEDGES + e];
        int pos = atomicAdd(&cursor[d], 1);
        eid[pos] = e;
    }
}

// ---------------- one-time: ea_s[t] = bf16(eattr[eid[t]] @ ew + eb), srcs[t]
// 4 edges per wave, all loads independent & in flight (latency fix).
__global__ __launch_bounds__(256) void ea_k(const float* __restrict__ eattr,
                                            const int* __restrict__ ei,
                                            const int* __restrict__ eid,
                                            const float* __restrict__ ew,
                                            const float* __restrict__ ebias,
                                            short* __restrict__ ea_s,
                                            int* __restrict__ srcs) {
    int lane = threadIdx.x & 63, wv = threadIdx.x >> 6;
    int c = lane * 4;
    float ewv[16][4];
#pragma unroll
    for (int k = 0; k < 16; ++k) {
        float4 v = *reinterpret_cast<const float4*>(ew + k * 256 + c);
        ewv[k][0] = v.x; ewv[k][1] = v.y; ewv[k][2] = v.z; ewv[k][3] = v.w;
    }
    float4 ebv = *reinterpret_cast<const float4*>(ebias + c);

    int t0 = (blockIdx.x * 4 + wv) * 4;
    if (t0 >= NEDGES) return;
    int4 e4 = *reinterpret_cast<const int4*>(eid + t0);
    int es[4] = { e4.x, e4.y, e4.z, e4.w };
    float4 q[4][4];
#pragma unroll
    for (int j = 0; j < 4; ++j) {
        const float4* ep = reinterpret_cast<const float4*>(eattr + (size_t)es[j] * 16);
        q[j][0] = ep[0]; q[j][1] = ep[1]; q[j][2] = ep[2]; q[j][3] = ep[3];
    }
    int s0 = ei[es[0]], s1 = ei[es[1]], s2 = ei[es[2]], s3 = ei[es[3]];
#pragma unroll
    for (int j = 0; j < 4; ++j) {
        float m[4] = { ebv.x, ebv.y, ebv.z, ebv.w };
        float ek[16] = { q[j][0].x, q[j][0].y, q[j][0].z, q[j][0].w,
                         q[j][1].x, q[j][1].y, q[j][1].z, q[j][1].w,
                         q[j][2].x, q[j][2].y, q[j][2].z, q[j][2].w,
                         q[j][3].x, q[j][3].y, q[j][3].z, q[j][3].w };
#pragma unroll
        for (int k = 0; k < 16; ++k)
#pragma unroll
            for (int i = 0; i < 4; ++i) m[i] = fmaf(ek[k], ewv[k][i], m[i]);
        u16x4 o;
#pragma unroll
        for (int i = 0; i < 4; ++i) o[i] = (unsigned short)f2b(m[i]);
        *reinterpret_cast<u16x4*>(ea_s + (size_t)(t0 + j) * HID + c) = o;
    }
    if (lane == 0) *reinterpret_cast<int4*>(srcs + t0) = make_int4(s0, s1, s2, s3);
}

// ------------------------------------------------- CSR aggregate, windowed
// Wave owns 4 consecutive nodes = one contiguous slot range. Process the
// range in windows of 8 slots (16 loads in flight), wave-uniform boundary
// walk flushes per node. zb[n] = hb[n] + sum relu(hb[src]+ea).
// Block 0 also zeroes the BN stats buffer (replaces a memset dispatch).
#define AGG_NPW 4
__global__ __launch_bounds__(256) void agg_k(
    const short* __restrict__ hb, const short* __restrict__ ea_s,
    const int* __restrict__ srcs, const int* __restrict__ row_ptr,
    short* __restrict__ zb, float* __restrict__ stats) {
    if (blockIdx.x == 0) {
        stats[threadIdx.x] = 0.f;
        stats[threadIdx.x + 256] = 0.f;
    }
    int lane = threadIdx.x & 63, wv = threadIdx.x >> 6;
    int c = lane * 4;
    int n0 = (blockIdx.x * 4 + wv) * AGG_NPW;   // grid exact: 3125*16 = 50000
    int t    = row_ptr[n0];
    int tEnd = row_ptr[n0 + AGG_NPW];
    int nextB = row_ptr[n0 + 1];
    int n = 0;
    u16x4 hcur = *reinterpret_cast<const u16x4*>(hb + (size_t)n0 * HID + c);
    u16x4 hnxt = *reinterpret_cast<const u16x4*>(hb + (size_t)(n0 + 1) * HID + c);
    float a0 = 0.f, a1 = 0.f, a2 = 0.f, a3 = 0.f;

#define AGG_FLUSH()                                                          \
    do {                                                                     \
        u16x4 o_;                                                            \
        o_[0] = (unsigned short)f2b(a0 + b2f(hcur[0]));                      \
        o_[1] = (unsigned short)f2b(a1 + b2f(hcur[1]));                      \
        o_[2] = (unsigned short)f2b(a2 + b2f(hcur[2]));                      \
        o_[3] = (unsigned short)f2b(a3 + b2f(hcur[3]));                      \
        *reinterpret_cast<u16x4*>(zb + (size_t)(n0 + n) * HID + c) = o_;     \
        hcur = hnxt;                                                         \
        int pn_ = n0 + n + 2;                                                \
        if (pn_ < NNODES)                                                    \
            hnxt = *reinterpret_cast<const u16x4*>(hb + (size_t)pn_ * HID + c); \
        a0 = a1 = a2 = a3 = 0.f;                                             \
        ++n;                                                                 \
        nextB = row_ptr[min(n0 + n + 1, NNODES)];                            \
    } while (0)

    while (true) {
        while (n < AGG_NPW && t == nextB) AGG_FLUSH();
        if (n >= AGG_NPW) break;
        int m = min(8, tEnd - t);
        int ss[8] = {0,0,0,0,0,0,0,0};
        u16x4 ev[8], gv[8];
#pragma unroll
        for (int k = 0; k < 8; ++k)
            if (k < m) ss[k] = srcs[t + k];
#pragma unroll
        for (int k = 0; k < 8; ++k)
            if (k < m) {
                ev[k] = *reinterpret_cast<const u16x4*>(ea_s + (size_t)(t + k) * HID + c);
                gv[k] = *reinterpret_cast<const u16x4*>(hb + (size_t)ss[k] * HID + c);
            }
#pragma unroll
        for (int k = 0; k < 8; ++k) {
            if (k < m) {
                while (n < AGG_NPW && t + k == nextB) AGG_FLUSH();
                a0 += fmaxf(b2f(ev[k][0]) + b2f(gv[k][0]), 0.f);
                a1 += fmaxf(b2f(ev[k][1]) + b2f(gv[k][1]), 0.f);
                a2 += fmaxf(b2f(ev[k][2]) + b2f(gv[k][2]), 0.f);
                a3 += fmaxf(b2f(ev[k][3]) + b2f(gv[k][3]), 0.f);
            }
        }
        t += m;
    }
#undef AGG_FLUSH
}

// ----------------------------------------------------------- bf16 MFMA GEMM
// C[M,256] = act(A@W + bias). BM=256 (4 waves x 64 rows), BN=64, K=256.
// B panel (64x256 bf16 = 32KB) in LDS (XOR swizzle); depth-1 A prefetch.
// Epilogue: per-wave LDS transpose (reusing Bs quarter) -> 1KB coalesced
// global_store_dwordx4 instead of 2B scattered stores.
template <bool RELU, bool STATS>
__global__ __launch_bounds__(256, 3) void gemm_k(const short* __restrict__ A,
                                                 const short* __restrict__ wT,
                                                 const float* __restrict__ bias,
                                                 short* __restrict__ C,
                                                 float* __restrict__ stats, int M) {
    __shared__ short Bs[64 * 256]; // 32KB
    char* BsB = (char*)Bs;
    int wv = threadIdx.x >> 6, lane = threadIdx.x & 63;
    int lr = lane & 15, lg = lane >> 4;
    int c0 = blockIdx.y * 64;
    int bm = blockIdx.x * 256;
    int r0 = bm + wv * 64;

    const char* panel = (const char*)(wT + (size_t)c0 * 256);
    {
        float4 v[4];
#pragma unroll
        for (int it = 0; it < 4; ++it)
            v[it] = *reinterpret_cast<const float4*>(panel + (threadIdx.x + it * 256) * 16);
#pragma unroll
        for (int it = 0; it < 4; ++it) {
            int o = (threadIdx.x + it * 256) * 16;
            int n = o >> 9;
            *reinterpret_cast<float4*>(BsB + (o ^ ((n & 7) << 4))) = v[it];
        }
        float4 v2[4];
#pragma unroll
        for (int it = 4; it < 8; ++it)
            v2[it - 4] = *reinterpret_cast<const float4*>(panel + (threadIdx.x + it * 256) * 16);
#pragma unroll
        for (int it = 4; it < 8; ++it) {
            int o = (threadIdx.x + it * 256) * 16;
            int n = o >> 9;
            *reinterpret_cast<float4*>(BsB + (o ^ ((n & 7) << 4))) = v2[it - 4];
        }
    }

    const short* pA[4];
    bool gok[4];
#pragma unroll
    for (int f = 0; f < 4; ++f) {
        int r = r0 + f * 16 + lr;
        gok[f] = r < M;
        pA[f] = A + (size_t)r * 256 + lg * 8;
    }

    f32x4 acc[4][4] = {};
    bf16x8 aCur[4] = {}, aNxt[4] = {};
#pragma unroll
    for (int f = 0; f < 4; ++f)
        if (gok[f]) aCur[f] = *reinterpret_cast<const bf16x8*>(pA[f]);

    __syncthreads();

    for (int k0 = 0; k0 < 256; k0 += 32) {
        if (k0 < 224) {
#pragma unroll
            for (int f = 0; f < 4; ++f)
                if (gok[f]) aNxt[f] = *reinterpret_cast<const bf16x8*>(pA[f] + k0 + 32);
        }
#pragma unroll
        for (int cc = 0; cc < 4; ++cc) {
            int n = cc * 16 + lr;
            int kb = k0 * 2 + lg * 16;
            bf16x8 b = *reinterpret_cast<const bf16x8*>(
                BsB + ((n * 512 + (kb ^ ((n & 7) << 4)))));
#pragma unroll
            for (int f = 0; f < 4; ++f)
                acc[f][cc] = __builtin_amdgcn_mfma_f32_16x16x32_bf16(aCur[f], b, acc[f][cc], 0, 0, 0);
        }
#pragma unroll
        for (int f = 0; f < 4; ++f) aCur[f] = aNxt[f];
    }

    // ---- epilogue: all waves done with B panel; reuse per-wave 8KB for C tile
    __syncthreads();
    char* S = BsB + wv * 8192;
#pragma unroll
    for (int cc = 0; cc < 4; ++cc) {
        int colL = cc * 16 + lr;
        float bi = bias[c0 + colL];
        float s = 0.f, ss2 = 0.f;
#pragma unroll
        for (int f = 0; f < 4; ++f)
#pragma unroll
            for (int i = 0; i < 4; ++i) {
                int rowL = f * 16 + lg * 4 + i;
                float v = acc[f][cc][i] + bi;
                if (RELU) v = fmaxf(v, 0.f);
                if (STATS && (r0 + rowL) < M) { s += v; ss2 = fmaf(v, v, ss2); }
                int byte = rowL * 128 + ((colL * 2) ^ ((rowL & 7) << 4));
                *reinterpret_cast<short*>(S + byte) = f2b(v);
            }
        if (STATS) {
            s   += __shfl_xor(s, 16);  ss2 += __shfl_xor(ss2, 16);
            s   += __shfl_xor(s, 32);  ss2 += __shfl_xor(ss2, 32);
            if (lg == 0) {
                atomicAdd(&stats[c0 + colL], s);
                atomicAdd(&stats[HID + c0 + colL], ss2);
            }
        }
    }
    asm volatile("s_waitcnt lgkmcnt(0)" ::: "memory");
#pragma unroll
    for (int j = 0; j < 8; ++j) {
        int rowL = j * 8 + (lane >> 3);
        int cb = (lane & 7) * 16;
        int byte = rowL * 128 + (cb ^ ((rowL & 7) << 4));
        int4 d = *reinterpret_cast<const int4*>(S + byte);
        int grow = r0 + rowL;
        if (grow < M)
            *reinterpret_cast<int4*>((char*)C + (size_t)grow * 512 + c0 * 2 + cb) = d;
    }
}

// ------------------------------------------------------- BN normalize+relu
__global__ void bn_relu_k(const short* __restrict__ z, short* __restrict__ hb,
                          const float* __restrict__ stats,
                          const float* __restrict__ gamma,
                          const float* __restrict__ beta) {
    int gidx = blockIdx.x * 256 + threadIdx.x;
    int base = gidx * 4;
    int j = base & 255;
    u16x4 z4 = *reinterpret_cast<const u16x4*>(z + base);
    u16x4 o;
#pragma unroll
    for (int i = 0; i < 4; ++i) {
        float mu  = stats[j + i] * (1.f / NNODES);
        float var = stats[HID + j + i] * (1.f / NNODES) - mu * mu;
        float inv = rsqrtf(var + 1e-5f);
        float v = (b2f(z4[i]) - mu) * inv * gamma[j + i] + beta[j + i];
        o[i] = (unsigned short)f2b(fmaxf(v, 0.f));
    }
    *reinterpret_cast<u16x4*>(hb + base) = o;
}

// ------------------------------------------------------------------ pool
#define PNB 64
__global__ void pool_k(const short* __restrict__ hb, const int* __restrict__ batch,
                       float* __restrict__ g) {
    int j = threadIdx.x;
    int n0 = blockIdx.x * PNB;
    int n1 = min(n0 + PNB, NNODES);
    int cur = batch[n0];
    float acc = 0.f;
    for (int n = n0; n < n1; ++n) {
        int b = batch[n];
        if (b != cur) {
            atomicAdd(&g[(size_t)cur * HID + j], acc);
            acc = 0.f; cur = b;
        }
        acc += b2f((unsigned short)hb[(size_t)n * HID + j]);
    }
    atomicAdd(&g[(size_t)cur * HID + j], acc);
}

// ------------------------------------------------------------------ head
__global__ void head_k(const float* __restrict__ g, const float* __restrict__ w1,
                       const float* __restrict__ b1, const float* __restrict__ w2,
                       const float* __restrict__ b2, float* __restrict__ out) {
    int gi = blockIdx.x;
    int j  = threadIdx.x;
    __shared__ float gr[256];
    __shared__ float hid[128];
    gr[j]       = g[gi * 256 + j];
    gr[j + 128] = g[gi * 256 + 128 + j];
    __syncthreads();
    float acc = b1[j];
    for (int k = 0; k < 256; ++k) acc = fmaf(gr[k], w1[k * 128 + j], acc);
    hid[j] = fmaxf(acc, 0.f);
    __syncthreads();
    if (j < 12) {
        float o = b2[j];
#pragma unroll
        for (int k = 0; k < 128; ++k) o = fmaf(hid[k], w2[k * 12 + j], o);
        out[gi * 12 + j] = o;
    }
}

// ---------------------------------------------------------------- launch
extern "C" void kernel_launch(void* const* d_in, const int* in_sizes, int n_in,
                              void* d_out, int out_size, void* d_ws, size_t ws_size,
                              hipStream_t stream) {
    const float* x     = (const float*)d_in[0];
    const int*   ei    = (const int*)d_in[1];
    const int*   batch = (const int*)d_in[2];
    const float* eattr = (const float*)d_in[3];
    const float* nw    = (const float*)d_in[4];
    const float* nb    = (const float*)d_in[5];
    const float* ew    = (const float*)d_in[6];
    const float* eb    = (const float*)d_in[7];
    const float* w1    = (const float*)d_in[8];
    const float* b1    = (const float*)d_in[9];
    const float* w2    = (const float*)d_in[10];
    const float* b2    = (const float*)d_in[11];
    const float* gam   = (const float*)d_in[12];
    const float* bet   = (const float*)d_in[13];
    const float* hw1   = (const float*)d_in[14];
    const float* hb1   = (const float*)d_in[15];
    const float* hw2   = (const float*)d_in[16];
    const float* hb2   = (const float*)d_in[17];
    float* out = (float*)d_out;

    const size_t NH = (size_t)NNODES * HID;
    const size_t EH = (size_t)NEDGES * HID;
    size_t off = 0;
    char* base = (char*)d_ws;
    auto alloc = [&](size_t bytes) -> void* {
        void* p = base + off;
        off += (bytes + 255) & ~(size_t)255;
        return p;
    };
    short* hb      = (short*)alloc(NH * 2);
    short* zb      = (short*)alloc(NH * 2);
    short* z1b     = (short*)alloc(NH * 2);
    short* wT      = (short*)alloc(8 * 65536 * 2);
    short* ea_s    = (short*)alloc(EH * 2);       // 153.6 MB, layer-invariant
    int*   srcs    = (int*)alloc((size_t)NEDGES * 4);
    float* stats   = (float*)alloc(512 * 4);
    float* g       = (float*)alloc((size_t)NGRAPHS * HID * 4);
    int*   deg     = (int*)alloc((size_t)NNODES * 4);
    int*   partial = (int*)alloc((size_t)NNODES * 4);
    int*   btot    = (int*)alloc(256 * 4);
    int*   row_ptr = (int*)alloc((size_t)(NNODES + 1) * 4);
    int*   cursor  = (int*)alloc((size_t)NNODES * 4);
    int*   eid     = (int*)alloc((size_t)NEDGES * 4);

    wconv_k<<<dim3(256, 4), 256, 0, stream>>>(w1, wT);
    wconv_k<<<dim3(256, 4), 256, 0, stream>>>(w2, wT + 4 * 65536);
    node_embed_k<<<NNODES, 256, 0, stream>>>(x, nw, nb, hb);

    hipMemsetAsync(deg, 0, (size_t)NNODES * 4, stream);
    deg_k<<<(NEDGES + 255) / 256, 256, 0, stream>>>(ei, deg);
    const int NB = (NNODES + 255) / 256;
    scan1_k<<<NB, 256, 0, stream>>>(deg, partial, btot);
    scan2_k<<<1, 256, 0, stream>>>(btot, NB);
    scan3_k<<<NB, 256, 0, stream>>>(deg, partial, btot, row_ptr, cursor);
    fill_k<<<(NEDGES + 255) / 256, 256, 0, stream>>>(ei, cursor, eid);
    ea_k<<<NEDGES / 16, 256, 0, stream>>>(eattr, ei, eid, ew, eb, ea_s, srcs);

    dim3 ggrid((NNODES + 255) / 256, 4);
    for (int l = 0; l < L; ++l) {
        agg_k<<<NNODES / (4 * AGG_NPW), 256, 0, stream>>>(
            hb, ea_s, srcs, row_ptr, zb, stats);
        gemm_k<true, false><<<ggrid, 256, 0, stream>>>(
            zb, wT + (size_t)l * 65536, b1 + l * HID, z1b, nullptr, NNODES);
        gemm_k<false, true><<<ggrid, 256, 0, stream>>>(
            z1b, wT + (size_t)(4 + l) * 65536, b2 + l * HID, zb, stats, NNODES);
        bn_relu_k<<<(int)(NH / 1024), 256, 0, stream>>>(
            zb, hb, stats, gam + l * HID, bet + l * HID);
    }

    hipMemsetAsync(g, 0, (size_t)NGRAPHS * HID * 4, stream);
    pool_k<<<(NNODES + PNB - 1) / PNB, 256, 0, stream>>>(hb, batch, g);
    head_k<<<NGRAPHS, 128, 0, stream>>>(g, hw1, hb1, hw2, hb2, out);
}